// Round 3
// baseline (244.009 us; speedup 1.0000x reference)
//
#include <hip/hip_runtime.h>

#define H_ 1080
#define W_ 1920
#define S_ 2000
#define C_ 8
#define HW_ (H_*W_)

// Single fused kernel, float32 output (reference outputs are int32/float32 ->
// harness buffer is float*). 4 pixels/thread: int4 spx load, float4 stores to
// all 29 planes. knn_dist/cent_dist are 64KB each -> L2-resident gathers.
__global__ __launch_bounds__(256) void fused_k(
    const int*   __restrict__ spx,
    const int*   __restrict__ knn_pred,
    const float* __restrict__ knn_dist,
    const float* __restrict__ cent_dist,
    float*       __restrict__ out)
{
  int t = blockIdx.x * blockDim.x + threadIdx.x;
  int p = t * 4;
  if (p >= HW_) return;

  int4 s4 = *reinterpret_cast<const int4*>(spx + p);
  int idx[4] = { s4.x - 1, s4.y - 1, s4.z - 1, s4.w - 1 };

  // preseg plane (float of int label)
  float4 pv;
  pv.x = (float)knn_pred[idx[0]];
  pv.y = (float)knn_pred[idx[1]];
  pv.z = (float)knn_pred[idx[2]];
  pv.w = (float)knn_pred[idx[3]];
  *reinterpret_cast<float4*>(out + p) = pv;

  // gather the two 8-float rows for each of the 4 pixels (2x float4 each)
  float kd[4][C_], cd[4][C_];
  #pragma unroll
  for (int q = 0; q < 4; ++q) {
    const float4* kr = reinterpret_cast<const float4*>(knn_dist  + idx[q] * C_);
    const float4* cr = reinterpret_cast<const float4*>(cent_dist + idx[q] * C_);
    float4 a = kr[0], b = kr[1], c = cr[0], d = cr[1];
    kd[q][0]=a.x; kd[q][1]=a.y; kd[q][2]=a.z; kd[q][3]=a.w;
    kd[q][4]=b.x; kd[q][5]=b.y; kd[q][6]=b.z; kd[q][7]=b.w;
    cd[q][0]=c.x; cd[q][1]=c.y; cd[q][2]=c.z; cd[q][3]=c.w;
    cd[q][4]=d.x; cd[q][5]=d.y; cd[q][6]=d.z; cd[q][7]=d.w;
  }

  // online top-2 max per row; with duplicates m2==m1, so the contrast
  // select (v==m1 ? m2 : m1) is exact even under ties.
  float km1[4], km2[4], cm1[4], cm2[4];
  #pragma unroll
  for (int q = 0; q < 4; ++q) {
    float m1 = -3.0e38f, m2 = -3.0e38f, n1 = -3.0e38f, n2 = -3.0e38f;
    #pragma unroll
    for (int k = 0; k < C_; ++k) {
      float v = kd[q][k];
      m2 = fmaxf(m2, fminf(v, m1));  m1 = fmaxf(m1, v);
      float u = cd[q][k];
      n2 = fmaxf(n2, fminf(u, n1));  n1 = fmaxf(n1, u);
    }
    km1[q]=m1; km2[q]=m2; cm1[q]=n1; cm2[q]=n2;
  }

  // attmaps planes: [class c=2..8][knn_att, knn_contrast, cent_att, cent_contrast]
  float* ao = out + HW_ + p;
  #pragma unroll
  for (int j = 1; j < C_; ++j) {
    float4 w0, w1, w2, w3;
    w0.x = kd[0][j]; w0.y = kd[1][j]; w0.z = kd[2][j]; w0.w = kd[3][j];
    w1.x = (kd[0][j]==km1[0]) ? km2[0] : km1[0];
    w1.y = (kd[1][j]==km1[1]) ? km2[1] : km1[1];
    w1.z = (kd[2][j]==km1[2]) ? km2[2] : km1[2];
    w1.w = (kd[3][j]==km1[3]) ? km2[3] : km1[3];
    w2.x = cd[0][j]; w2.y = cd[1][j]; w2.z = cd[2][j]; w2.w = cd[3][j];
    w3.x = (cd[0][j]==cm1[0]) ? cm2[0] : cm1[0];
    w3.y = (cd[1][j]==cm1[1]) ? cm2[1] : cm1[1];
    w3.z = (cd[2][j]==cm1[2]) ? cm2[2] : cm1[2];
    w3.w = (cd[3][j]==cm1[3]) ? cm2[3] : cm1[3];

    size_t b = (size_t)(j - 1) * 4 * HW_;
    *reinterpret_cast<float4*>(ao + b            ) = w0;
    *reinterpret_cast<float4*>(ao + b +     HW_  ) = w1;
    *reinterpret_cast<float4*>(ao + b + 2 * HW_  ) = w2;
    *reinterpret_cast<float4*>(ao + b + 3 * HW_  ) = w3;
  }
}

extern "C" void kernel_launch(void* const* d_in, const int* in_sizes, int n_in,
                              void* d_out, int out_size, void* d_ws, size_t ws_size,
                              hipStream_t stream)
{
  const int*   spx       = (const int*)  d_in[0];   // (1,1,H,W) int32, labels 1..S
  const int*   knn_pred  = (const int*)  d_in[1];   // (S,) int32
  const float* knn_dist  = (const float*)d_in[2];   // (S,C) f32
  const float* cent_dist = (const float*)d_in[3];   // (S,C) f32
  float* out = (float*)d_out;                       // 29*HW float32

  const int nthreads = HW_ / 4;                     // 518400, exact
  fused_k<<<(nthreads + 255) / 256, 256, 0, stream>>>(spx, knn_pred, knn_dist, cent_dist, out);
}